// Round 5
// baseline (387.080 us; speedup 1.0000x reference)
//
#include <hip/hip_runtime.h>
#include <math.h>

#define NB 4
#define NT 2048
#define ND 1024
#define NH 16
#define NHD 64
#define N3D 3072
#define M1 8192

typedef __attribute__((ext_vector_type(8))) short bf16x8;
typedef __attribute__((ext_vector_type(4))) float f32x4;
typedef __attribute__((ext_vector_type(16))) float f32x16;
typedef __attribute__((ext_vector_type(2))) int i32x2;
typedef unsigned short u16;
typedef unsigned int u32;

__device__ __forceinline__ u32 bf16rn(float f) {
    u32 u = __float_as_uint(f);
    return (u + 0x7FFFu + ((u >> 16) & 1u)) >> 16;
}
__device__ __forceinline__ u32 pack2(float a, float b) {
    return bf16rn(a) | (bf16rn(b) << 16);
}
__device__ __forceinline__ u32 cvtpk(float lo, float hi) {
    u32 r;
    asm("v_cvt_pk_bf16_f32 %0, %1, %2" : "=v"(r) : "v"(lo), "v"(hi));
    return r;
}
// exchange a.hi-lanes <-> b.lo-lanes:  a' = {a.lo | b.lo-data}, b' = {a.hi-data | b.hi}
__device__ __forceinline__ void pswap(u32& a, u32& b) {
    i32x2 r = __builtin_amdgcn_permlane32_swap((int)a, (int)b, false, false);
    a = (u32)r.x; b = (u32)r.y;
}

// ---------- convert x fp32 -> bf16 ----------
__global__ __launch_bounds__(256) void convx_kernel(const float* __restrict__ in, u16* __restrict__ out) {
    const int idx = blockIdx.x * 256 + threadIdx.x;
    const float4 v = *reinterpret_cast<const float4*>(in + (size_t)idx * 4);
    *reinterpret_cast<uint2*>(out + (size_t)idx * 4) = make_uint2(pack2(v.x, v.y), pack2(v.z, v.w));
}

// ---------- transpose + convert: fp32 [R][C] -> bf16 [C][R] ----------
__global__ __launch_bounds__(256) void tconv_kernel(const float* __restrict__ in, u16* __restrict__ out,
                                                    int R, int C) {
    __shared__ float t[32][33];
    const int bx = blockIdx.x * 32, by = blockIdx.y * 32;
    const int x = threadIdx.x, y0 = threadIdx.y;
    #pragma unroll
    for (int yy = y0; yy < 32; yy += 8) t[yy][x] = in[(size_t)(by + yy) * C + bx + x];
    __syncthreads();
    #pragma unroll
    for (int yy = y0; yy < 32; yy += 8) out[(size_t)(bx + yy) * R + by + x] = (u16)bf16rn(t[x][yy]);
}

// ---------- bf16 MFMA GEMM core (128x128 tile, BK=32, 4 waves) ----------
// OPERANDS SWAPPED: acc = mfma(bF, aF) => acc holds C^T fragments:
//   lane (g=lane>>4, col=lane&15), reg r:  C[m = m0+wr*64+mm*16+col][n = n0+wc*64+nn*16+g*4+r]
// => 4 n-adjacent values per lane: coalesced packed stores without LDS repack.
#define GEMM_PROLOGUE(Aptr, Btptr)                                                            \
    __shared__ __align__(16) u16 As[4096];                                                    \
    __shared__ __align__(16) u16 Bs[4096];                                                    \
    const int tid = threadIdx.x;                                                              \
    const int lane = tid & 63, wave = tid >> 6;                                               \
    const int wr = wave >> 1, wc = wave & 1;                                                  \
    const int n0 = blockIdx.x * 128, m0 = blockIdx.y * 128;                                   \
    const int c0 = tid, c1 = tid + 256;                                                       \
    const int pA0 = (c0 * 16) ^ ((((c0 * 16) >> 6) & 7) << 4);                                \
    const int pA1 = (c1 * 16) ^ ((((c1 * 16) >> 6) & 7) << 4);                                \
    const u16* gA0 = Aptr + (size_t)(m0 + (c0 >> 2)) * 1024 + (c0 & 3) * 8;                   \
    const u16* gA1 = Aptr + (size_t)(m0 + (c1 >> 2)) * 1024 + (c1 & 3) * 8;                   \
    const u16* gB0 = Btptr + (size_t)(n0 + (c0 >> 2)) * 1024 + (c0 & 3) * 8;                  \
    const u16* gB1 = Btptr + (size_t)(n0 + (c1 >> 2)) * 1024 + (c1 & 3) * 8;                  \
    int offA[4], offB[4];                                                                     \
    {                                                                                         \
        const int kb = (lane >> 4) * 16;                                                      \
        _Pragma("unroll")                                                                     \
        for (int mm = 0; mm < 4; ++mm) {                                                      \
            int row = wr * 64 + mm * 16 + (lane & 15);                                        \
            offA[mm] = (row * 64 + kb) ^ ((row & 7) << 4);                                    \
        }                                                                                     \
        _Pragma("unroll")                                                                     \
        for (int nn = 0; nn < 4; ++nn) {                                                      \
            int row = wc * 64 + nn * 16 + (lane & 15);                                        \
            offB[nn] = (row * 64 + kb) ^ ((row & 7) << 4);                                    \
        }                                                                                     \
    }                                                                                         \
    f32x4 acc[4][4];                                                                          \
    _Pragma("unroll")                                                                         \
    for (int mm = 0; mm < 4; ++mm)                                                            \
        _Pragma("unroll")                                                                     \
        for (int nn = 0; nn < 4; ++nn)                                                        \
            acc[mm][nn] = (f32x4){0.f, 0.f, 0.f, 0.f};                                        \
    uint4 va0 = *(const uint4*)gA0, va1 = *(const uint4*)gA1;                                 \
    uint4 vb0 = *(const uint4*)gB0, vb1 = *(const uint4*)gB1;                                 \
    for (int k0 = 0; k0 < 1024; k0 += 32) {                                                   \
        __syncthreads();                                                                      \
        *(uint4*)((char*)As + pA0) = va0;                                                     \
        *(uint4*)((char*)As + pA1) = va1;                                                     \
        *(uint4*)((char*)Bs + pA0) = vb0;                                                     \
        *(uint4*)((char*)Bs + pA1) = vb1;                                                     \
        __syncthreads();                                                                      \
        if (k0 + 32 < 1024) {                                                                 \
            gA0 += 32; gA1 += 32; gB0 += 32; gB1 += 32;                                       \
            va0 = *(const uint4*)gA0; va1 = *(const uint4*)gA1;                               \
            vb0 = *(const uint4*)gB0; vb1 = *(const uint4*)gB1;                               \
        }                                                                                     \
        bf16x8 aF[4], bF[4];                                                                  \
        _Pragma("unroll")                                                                     \
        for (int mm = 0; mm < 4; ++mm) aF[mm] = *(const bf16x8*)((const char*)As + offA[mm]); \
        _Pragma("unroll")                                                                     \
        for (int nn = 0; nn < 4; ++nn) bF[nn] = *(const bf16x8*)((const char*)Bs + offB[nn]); \
        _Pragma("unroll")                                                                     \
        for (int mm = 0; mm < 4; ++mm)                                                        \
            _Pragma("unroll")                                                                 \
            for (int nn = 0; nn < 4; ++nn)                                                    \
                acc[mm][nn] = __builtin_amdgcn_mfma_f32_16x16x32_bf16(bF[nn], aF[mm],         \
                                                                      acc[mm][nn], 0, 0, 0); \
    }

// qkv GEMM: bf16 Q (pre-scaled) [bh][t][d], bf16 K [bh][t][d], bf16 V TRANSPOSED [bh][d][t]
__global__ __launch_bounds__(256) void gemm_qkv_kernel(
    const u16* __restrict__ A, const u16* __restrict__ Bt,
    u16* __restrict__ Qo, u16* __restrict__ Ko, u16* __restrict__ Vo)
{
    GEMM_PROLOGUE(A, Bt)
    const float qsc = 0.18033688011112042f;  // 0.125 * log2(e)
    const int col16 = lane & 15, g4 = (lane >> 4) << 2;
    const int nb0 = n0 + wc * 64;
    const int tb0 = m0 + wr * 64;
    const int s = nb0 >> 10;                 // uniform per wave
    if (s == 0) {
        #pragma unroll
        for (int mm = 0; mm < 4; ++mm) {
            const int t = tb0 + mm * 16 + col16;
            const int bq = t >> 11, tt = t & 2047;
            #pragma unroll
            for (int nn = 0; nn < 4; ++nn) {
                const int n_abs = nb0 + nn * 16 + g4;
                const int hh = (n_abs >> 6) & 15, hd = n_abs & 63;
                uint2 w = make_uint2(pack2(acc[mm][nn][0] * qsc, acc[mm][nn][1] * qsc),
                                     pack2(acc[mm][nn][2] * qsc, acc[mm][nn][3] * qsc));
                *reinterpret_cast<uint2*>(&Qo[((size_t)((bq << 4) + hh) * 2048 + tt) * 64 + hd]) = w;
            }
        }
    } else if (s == 1) {
        #pragma unroll
        for (int mm = 0; mm < 4; ++mm) {
            const int t = tb0 + mm * 16 + col16;
            const int bq = t >> 11, tt = t & 2047;
            #pragma unroll
            for (int nn = 0; nn < 4; ++nn) {
                const int n_abs = nb0 + nn * 16 + g4;
                const int hh = (n_abs >> 6) & 15, hd = n_abs & 63;
                uint2 w = make_uint2(pack2(acc[mm][nn][0], acc[mm][nn][1]),
                                     pack2(acc[mm][nn][2], acc[mm][nn][3]));
                *reinterpret_cast<uint2*>(&Ko[((size_t)((bq << 4) + hh) * 2048 + tt) * 64 + hd]) = w;
            }
        }
    } else {
        #pragma unroll
        for (int mm = 0; mm < 4; ++mm) {
            const int t = tb0 + mm * 16 + col16;
            const int bq = t >> 11, tt = t & 2047;
            #pragma unroll
            for (int nn = 0; nn < 4; ++nn) {
                const int n_abs = nb0 + nn * 16 + g4;
                const int hh = (n_abs >> 6) & 15, hd = n_abs & 63;
                const size_t vbase = ((size_t)((bq << 4) + hh) * 64 + hd) * 2048 + tt;
                #pragma unroll
                for (int r = 0; r < 4; ++r)
                    Vo[vbase + (size_t)r * 2048] = (u16)bf16rn(acc[mm][nn][r]);
            }
        }
    }
}

// out GEMM: fp32 C row-major, float4 stores (C^T acc => 4 n-adjacent per lane)
__global__ __launch_bounds__(256) void gemm_out_kernel(
    const u16* __restrict__ A, const u16* __restrict__ Bt, float* __restrict__ C)
{
    GEMM_PROLOGUE(A, Bt)
    const int col16 = lane & 15, g4 = (lane >> 4) << 2;
    #pragma unroll
    for (int mm = 0; mm < 4; ++mm) {
        const int m = m0 + wr * 64 + mm * 16 + col16;
        #pragma unroll
        for (int nn = 0; nn < 4; ++nn) {
            const int n_a = n0 + wc * 64 + nn * 16 + g4;
            *reinterpret_cast<float4*>(&C[(size_t)m * 1024 + n_a]) =
                make_float4(acc[mm][nn][0], acc[mm][nn][1], acc[mm][nn][2], acc[mm][nn][3]);
        }
    }
}

// ---------- MFMA flash attention, 32x32x16 + cvt_pk/permlane32_swap ----------
// grid 1024 (XCD-swizzled), block 256 = 4 waves; wave owns 32 q rows, 32-key tiles.
// S^T = mfma(K, Q): lane (hi=l>>5, col=l&31) holds 16 k-rows of q=col:
//   k(reg) = (reg&3) + 8*(reg>>2) + 4*hi. Softmax lane-local + 1 shfl_xor(32).
// P^T B-frags: 8 cvt_pk + 4 permlane32_swap (no DS ops). PV: O^T = mfma(V^T, P^T).
__global__ __launch_bounds__(256) void attn4_kernel(
    const u16* __restrict__ Q, const u16* __restrict__ K, const u16* __restrict__ Vt,
    const int* __restrict__ pos, u16* __restrict__ AO)
{
    __shared__ int bndS[128];

    const int wg = ((blockIdx.x & 7) << 7) + (blockIdx.x >> 3);  // bijective XCD swizzle
    const int bh = wg >> 4;
    const int qb = 15 - (wg & 15);                               // longest prefixes first
    const int b = bh >> 4, h = bh & 15;
    const int tid = threadIdx.x, lane = tid & 63, wave = tid >> 6;
    const int col = lane & 31, hi = lane >> 5;

    // per-row attended-prefix bound: first index with pos > pos_row (exact, 12 iters)
    if (tid < 128) {
        const int target = pos[b * 2048 + qb * 128 + tid];
        int lo = 0, hic = 2048;
        #pragma unroll
        for (int it = 0; it < 12; ++it) {
            const int mid = (lo + hic) >> 1;
            if (lo < hic) { if (pos[b * 2048 + mid] <= target) lo = mid + 1; else hic = mid; }
        }
        bndS[tid] = lo;
    }
    __syncthreads();

    const int bnd     = bndS[wave * 32 + col];
    const int bnd_min = bndS[wave * 32];
    const int bnd_max = bndS[wave * 32 + 31];

    const int i0 = qb * 128 + wave * 32;
    const size_t kvrow = (size_t)bh * 2048;
    const size_t vrow  = (size_t)bh * 64;

    // Q B-frags (pre-scaled by 0.125*log2e): lane reads Q[i0+col][ds*16 + hi*8 ..+8]
    bf16x8 qf[4];
    #pragma unroll
    for (int ds = 0; ds < 4; ++ds)
        qf[ds] = *(const bf16x8*)&Q[(kvrow + i0 + col) * 64 + ds * 16 + hi * 8];

    const int hi4 = 4 * hi;

    float mrun = -INFINITY, lrun = 0.f;
    f32x16 oT0, oT1;
    #pragma unroll
    for (int i = 0; i < 16; ++i) { oT0[i] = 0.f; oT1[i] = 0.f; }

    // preload tile 0 fragments
    bf16x8 kf[4], vfa[2], vfb[2];
    #pragma unroll
    for (int ds = 0; ds < 4; ++ds)
        kf[ds] = *(const bf16x8*)&K[(kvrow + col) * 64 + ds * 16 + hi * 8];
    #pragma unroll
    for (int kh = 0; kh < 2; ++kh) {
        vfa[kh] = *(const bf16x8*)&Vt[(vrow + col) * 2048 + kh * 16 + hi * 8];
        vfb[kh] = *(const bf16x8*)&Vt[(vrow + 32 + col) * 2048 + kh * 16 + hi * 8];
    }

    for (int j0 = 0; j0 < bnd_max; j0 += 32) {
        // S^T = K · Q^T over d=64 (4 chained K=16 mfmas)
        f32x16 st;
        #pragma unroll
        for (int i = 0; i < 16; ++i) st[i] = 0.f;
        #pragma unroll
        for (int ds = 0; ds < 4; ++ds)
            st = __builtin_amdgcn_mfma_f32_32x32x16_bf16(kf[ds], qf[ds], st, 0, 0, 0);

        // prefetch next tile
        const int jn = (j0 + 32 < bnd_max) ? j0 + 32 : j0;
        bf16x8 kf2[4], vna[2], vnb[2];
        #pragma unroll
        for (int ds = 0; ds < 4; ++ds)
            kf2[ds] = *(const bf16x8*)&K[(kvrow + jn + col) * 64 + ds * 16 + hi * 8];
        #pragma unroll
        for (int kh = 0; kh < 2; ++kh) {
            vna[kh] = *(const bf16x8*)&Vt[(vrow + col) * 2048 + jn + kh * 16 + hi * 8];
            vnb[kh] = *(const bf16x8*)&Vt[(vrow + 32 + col) * 2048 + jn + kh * 16 + hi * 8];
        }

        // mask: k_global >= bnd(q)
        if (j0 + 32 > bnd_min) {
            #pragma unroll
            for (int r = 0; r < 16; ++r) {
                const int kg = j0 + ((r & 3) + 8 * (r >> 2)) + hi4;
                if (kg >= bnd) st[r] = -INFINITY;
            }
        }

        // online softmax (exp2 domain; Q pre-scaled)
        float rm = st[0];
        #pragma unroll
        for (int r = 1; r < 16; ++r) rm = fmaxf(rm, st[r]);
        rm = fmaxf(rm, __shfl_xor(rm, 32));
        const float mnew = fmaxf(mrun, rm);
        const float factor = __builtin_amdgcn_exp2f(mrun - mnew);
        mrun = mnew;
        float psum = 0.f;
        #pragma unroll
        for (int r = 0; r < 16; ++r) {
            const float p = __builtin_amdgcn_exp2f(st[r] - mnew);
            st[r] = p;
            psum += p;
        }
        psum += __shfl_xor(psum, 32);
        lrun = lrun * factor + psum;
        #pragma unroll
        for (int i = 0; i < 16; ++i) { oT0[i] *= factor; oT1[i] *= factor; }

        // pack P^T: W[r] covers k-pair {8*(r>>1) + 2*(r&1) + 4hi, +1}
        u32 W[8];
        #pragma unroll
        for (int r = 0; r < 8; ++r) W[r] = cvtpk(st[2 * r], st[2 * r + 1]);

        // build B-frags via permlane32_swap: pf[0] = k[0,16), pf[1] = k[16,32)
        u32 a0 = W[0], b0 = W[2]; pswap(a0, b0);
        u32 a1 = W[1], b1 = W[3]; pswap(a1, b1);
        u32 a2 = W[4], b2 = W[6]; pswap(a2, b2);
        u32 a3 = W[5], b3 = W[7]; pswap(a3, b3);
        union { u32 w[4]; bf16x8 v; } p0, p1;
        p0.w[0] = a0; p0.w[1] = a1; p0.w[2] = b0; p0.w[3] = b1;
        p1.w[0] = a2; p1.w[1] = a3; p1.w[2] = b2; p1.w[3] = b3;

        // PV: O^T += V^T · P^T  (d rows 0-31 in oT0, 32-63 in oT1)
        oT0 = __builtin_amdgcn_mfma_f32_32x32x16_bf16(vfa[0], p0.v, oT0, 0, 0, 0);
        oT0 = __builtin_amdgcn_mfma_f32_32x32x16_bf16(vfa[1], p1.v, oT0, 0, 0, 0);
        oT1 = __builtin_amdgcn_mfma_f32_32x32x16_bf16(vfb[0], p0.v, oT1, 0, 0, 0);
        oT1 = __builtin_amdgcn_mfma_f32_32x32x16_bf16(vfb[1], p1.v, oT1, 0, 0, 0);

        #pragma unroll
        for (int ds = 0; ds < 4; ++ds) kf[ds] = kf2[ds];
        #pragma unroll
        for (int kh = 0; kh < 2; ++kh) { vfa[kh] = vna[kh]; vfb[kh] = vnb[kh]; }
    }

    // epilogue: scale by 1/l, pack d-pairs, write AO bf16 [t][h*64+d]
    const float inv = 1.f / lrun;
    u16* dst = &AO[((size_t)(b * 2048 + i0 + col)) * 1024 + h * 64];
    #pragma unroll
    for (int w = 0; w < 8; ++w) {
        const int dloc = 8 * (w >> 1) + 2 * (w & 1) + hi4;
        *reinterpret_cast<u32*>(&dst[dloc])      = cvtpk(oT0[2 * w] * inv, oT0[2 * w + 1] * inv);
        *reinterpret_cast<u32*>(&dst[32 + dloc]) = cvtpk(oT1[2 * w] * inv, oT1[2 * w + 1] * inv);
    }
}

extern "C" void kernel_launch(void* const* d_in, const int* in_sizes, int n_in,
                              void* d_out, int out_size, void* d_ws, size_t ws_size,
                              hipStream_t stream) {
    (void)in_sizes; (void)n_in; (void)out_size; (void)ws_size;
    const float* x    = (const float*)d_in[0];
    const int*   pos  = (const int*)d_in[1];
    const float* Wqkv = (const float*)d_in[2];
    const float* Wout = (const float*)d_in[3];
    float* out = (float*)d_out;

    char* ws = (char*)d_ws;
    u16* xb    = (u16*)(ws);                 // 16 MB (aliased as AO after gemm1 consumes it)
    u16* WqkvT = (u16*)(ws + 16777216);      // 6 MB
    u16* WoutT = (u16*)(ws + 23068672);      // 2 MB
    u16* Qb    = (u16*)(ws + 25165824);      // 16 MB bf16 [bh][t][d], pre-scaled
    u16* Kb    = (u16*)(ws + 41943040);      // 16 MB bf16 [bh][t][d]
    u16* Vtb   = (u16*)(ws + 58720256);      // 16 MB bf16 [bh][d][t] (written transposed by gemm)
    u16* AO    = xb;

    convx_kernel<<<dim3(M1 * ND / (256 * 4)), dim3(256), 0, stream>>>(x, xb);
    tconv_kernel<<<dim3(N3D / 32, ND / 32), dim3(32, 8), 0, stream>>>(Wqkv, WqkvT, ND, N3D);
    tconv_kernel<<<dim3(ND / 32, ND / 32), dim3(32, 8), 0, stream>>>(Wout, WoutT, ND, ND);
    gemm_qkv_kernel<<<dim3(N3D / 128, M1 / 128), dim3(256), 0, stream>>>(xb, WqkvT, Qb, Kb, Vtb);
    attn4_kernel<<<dim3(1024), dim3(256), 0, stream>>>(Qb, Kb, Vtb, pos, AO);
    gemm_out_kernel<<<dim3(ND / 128, M1 / 128), dim3(256), 0, stream>>>(AO, WoutT, out);
}

// Round 6
// 356.629 us; speedup vs baseline: 1.0854x; 1.0854x over previous
//
#include <hip/hip_runtime.h>
#include <math.h>

#define NB 4
#define NT 2048
#define ND 1024
#define NH 16
#define NHD 64
#define N3D 3072
#define M1 8192

typedef __attribute__((ext_vector_type(8))) short bf16x8;
typedef __attribute__((ext_vector_type(4))) float f32x4;
typedef __attribute__((ext_vector_type(16))) float f32x16;
typedef __attribute__((ext_vector_type(2))) int i32x2;
typedef unsigned short u16;
typedef unsigned int u32;

__device__ __forceinline__ u32 bf16rn(float f) {
    u32 u = __float_as_uint(f);
    return (u + 0x7FFFu + ((u >> 16) & 1u)) >> 16;
}
__device__ __forceinline__ u32 pack2(float a, float b) {
    return bf16rn(a) | (bf16rn(b) << 16);
}
__device__ __forceinline__ u32 cvtpk(float lo, float hi) {
    u32 r;
    asm("v_cvt_pk_bf16_f32 %0, %1, %2" : "=v"(r) : "v"(lo), "v"(hi));
    return r;
}
__device__ __forceinline__ void pswap(u32& a, u32& b) {
    i32x2 r = __builtin_amdgcn_permlane32_swap((int)a, (int)b, false, false);
    a = (u32)r.x; b = (u32)r.y;
}

// ---------- convert x fp32 -> bf16 ----------
__global__ __launch_bounds__(256) void convx_kernel(const float* __restrict__ in, u16* __restrict__ out) {
    const int idx = blockIdx.x * 256 + threadIdx.x;
    const float4 v = *reinterpret_cast<const float4*>(in + (size_t)idx * 4);
    *reinterpret_cast<uint2*>(out + (size_t)idx * 4) = make_uint2(pack2(v.x, v.y), pack2(v.z, v.w));
}

// ---------- transpose + convert: fp32 [R][C] -> bf16 [C][R] ----------
__global__ __launch_bounds__(256) void tconv_kernel(const float* __restrict__ in, u16* __restrict__ out,
                                                    int R, int C) {
    __shared__ float t[32][33];
    const int bx = blockIdx.x * 32, by = blockIdx.y * 32;
    const int x = threadIdx.x, y0 = threadIdx.y;
    #pragma unroll
    for (int yy = y0; yy < 32; yy += 8) t[yy][x] = in[(size_t)(by + yy) * C + bx + x];
    __syncthreads();
    #pragma unroll
    for (int yy = y0; yy < 32; yy += 8) out[(size_t)(bx + yy) * R + by + x] = (u16)bf16rn(t[x][yy]);
}

// ---------- bf16 MFMA GEMM core (128x128 tile, BK=32, 4 waves) ----------
// OPERANDS SWAPPED: acc = mfma(bF, aF) => acc holds C^T fragments:
//   lane (g=lane>>4, col=lane&15), reg r:  C[m0+wr*64+mm*16+col][n0+wc*64+nn*16+g*4+r]
#define GEMM_PROLOGUE(Aptr, Btptr)                                                            \
    __shared__ __align__(16) u16 As[4096];                                                    \
    __shared__ __align__(16) u16 Bs[4096];                                                    \
    const int tid = threadIdx.x;                                                              \
    const int lane = tid & 63, wave = tid >> 6;                                               \
    const int wr = wave >> 1, wc = wave & 1;                                                  \
    const int n0 = blockIdx.x * 128, m0 = blockIdx.y * 128;                                   \
    const int c0 = tid, c1 = tid + 256;                                                      \
    const int pA0 = (c0 * 16) ^ ((((c0 * 16) >> 6) & 7) << 4);                                \
    const int pA1 = (c1 * 16) ^ ((((c1 * 16) >> 6) & 7) << 4);                                \
    const u16* gA0 = Aptr + (size_t)(m0 + (c0 >> 2)) * 1024 + (c0 & 3) * 8;                   \
    const u16* gA1 = Aptr + (size_t)(m0 + (c1 >> 2)) * 1024 + (c1 & 3) * 8;                   \
    const u16* gB0 = Btptr + (size_t)(n0 + (c0 >> 2)) * 1024 + (c0 & 3) * 8;                  \
    const u16* gB1 = Btptr + (size_t)(n0 + (c1 >> 2)) * 1024 + (c1 & 3) * 8;                  \
    int offA[4], offB[4];                                                                     \
    {                                                                                         \
        const int kb = (lane >> 4) * 16;                                                      \
        _Pragma("unroll")                                                                     \
        for (int mm = 0; mm < 4; ++mm) {                                                      \
            int row = wr * 64 + mm * 16 + (lane & 15);                                        \
            offA[mm] = (row * 64 + kb) ^ ((row & 7) << 4);                                    \
        }                                                                                     \
        _Pragma("unroll")                                                                     \
        for (int nn = 0; nn < 4; ++nn) {                                                      \
            int row = wc * 64 + nn * 16 + (lane & 15);                                        \
            offB[nn] = (row * 64 + kb) ^ ((row & 7) << 4);                                    \
        }                                                                                     \
    }                                                                                         \
    f32x4 acc[4][4];                                                                          \
    _Pragma("unroll")                                                                         \
    for (int mm = 0; mm < 4; ++mm)                                                            \
        _Pragma("unroll")                                                                     \
        for (int nn = 0; nn < 4; ++nn)                                                        \
            acc[mm][nn] = (f32x4){0.f, 0.f, 0.f, 0.f};                                        \
    uint4 va0 = *(const uint4*)gA0, va1 = *(const uint4*)gA1;                                 \
    uint4 vb0 = *(const uint4*)gB0, vb1 = *(const uint4*)gB1;                                 \
    for (int k0 = 0; k0 < 1024; k0 += 32) {                                                   \
        __syncthreads();                                                                      \
        *(uint4*)((char*)As + pA0) = va0;                                                     \
        *(uint4*)((char*)As + pA1) = va1;                                                     \
        *(uint4*)((char*)Bs + pA0) = vb0;                                                     \
        *(uint4*)((char*)Bs + pA1) = vb1;                                                     \
        __syncthreads();                                                                      \
        if (k0 + 32 < 1024) {                                                                 \
            gA0 += 32; gA1 += 32; gB0 += 32; gB1 += 32;                                       \
            va0 = *(const uint4*)gA0; va1 = *(const uint4*)gA1;                               \
            vb0 = *(const uint4*)gB0; vb1 = *(const uint4*)gB1;                               \
        }                                                                                     \
        bf16x8 aF[4], bF[4];                                                                  \
        _Pragma("unroll")                                                                     \
        for (int mm = 0; mm < 4; ++mm) aF[mm] = *(const bf16x8*)((const char*)As + offA[mm]); \
        _Pragma("unroll")                                                                     \
        for (int nn = 0; nn < 4; ++nn) bF[nn] = *(const bf16x8*)((const char*)Bs + offB[nn]); \
        _Pragma("unroll")                                                                     \
        for (int mm = 0; mm < 4; ++mm)                                                        \
            _Pragma("unroll")                                                                 \
            for (int nn = 0; nn < 4; ++nn)                                                    \
                acc[mm][nn] = __builtin_amdgcn_mfma_f32_16x16x32_bf16(bF[nn], aF[mm],         \
                                                                      acc[mm][nn], 0, 0, 0); \
    }

// qkv GEMM: bf16 Q (pre-scaled) [bh][t][d], bf16 K [bh][t][d], bf16 V TRANSPOSED [bh][d][t]
__global__ __launch_bounds__(256) void gemm_qkv_kernel(
    const u16* __restrict__ A, const u16* __restrict__ Bt,
    u16* __restrict__ Qo, u16* __restrict__ Ko, u16* __restrict__ Vo)
{
    GEMM_PROLOGUE(A, Bt)
    const float qsc = 0.18033688011112042f;  // 0.125 * log2(e)
    const int col16 = lane & 15, g4 = (lane >> 4) << 2;
    const int nb0 = n0 + wc * 64;
    const int tb0 = m0 + wr * 64;
    const int s = nb0 >> 10;                 // uniform per wave
    if (s == 0) {
        #pragma unroll
        for (int mm = 0; mm < 4; ++mm) {
            const int t = tb0 + mm * 16 + col16;
            const int bq = t >> 11, tt = t & 2047;
            #pragma unroll
            for (int nn = 0; nn < 4; ++nn) {
                const int n_abs = nb0 + nn * 16 + g4;
                const int hh = (n_abs >> 6) & 15, hd = n_abs & 63;
                uint2 w = make_uint2(pack2(acc[mm][nn][0] * qsc, acc[mm][nn][1] * qsc),
                                     pack2(acc[mm][nn][2] * qsc, acc[mm][nn][3] * qsc));
                *reinterpret_cast<uint2*>(&Qo[((size_t)((bq << 4) + hh) * 2048 + tt) * 64 + hd]) = w;
            }
        }
    } else if (s == 1) {
        #pragma unroll
        for (int mm = 0; mm < 4; ++mm) {
            const int t = tb0 + mm * 16 + col16;
            const int bq = t >> 11, tt = t & 2047;
            #pragma unroll
            for (int nn = 0; nn < 4; ++nn) {
                const int n_abs = nb0 + nn * 16 + g4;
                const int hh = (n_abs >> 6) & 15, hd = n_abs & 63;
                uint2 w = make_uint2(pack2(acc[mm][nn][0], acc[mm][nn][1]),
                                     pack2(acc[mm][nn][2], acc[mm][nn][3]));
                *reinterpret_cast<uint2*>(&Ko[((size_t)((bq << 4) + hh) * 2048 + tt) * 64 + hd]) = w;
            }
        }
    } else {
        #pragma unroll
        for (int mm = 0; mm < 4; ++mm) {
            const int t = tb0 + mm * 16 + col16;
            const int bq = t >> 11, tt = t & 2047;
            #pragma unroll
            for (int nn = 0; nn < 4; ++nn) {
                const int n_abs = nb0 + nn * 16 + g4;
                const int hh = (n_abs >> 6) & 15, hd = n_abs & 63;
                const size_t vbase = ((size_t)((bq << 4) + hh) * 64 + hd) * 2048 + tt;
                #pragma unroll
                for (int r = 0; r < 4; ++r)
                    Vo[vbase + (size_t)r * 2048] = (u16)bf16rn(acc[mm][nn][r]);
            }
        }
    }
}

// out GEMM: fp32 C row-major, float4 stores
__global__ __launch_bounds__(256) void gemm_out_kernel(
    const u16* __restrict__ A, const u16* __restrict__ Bt, float* __restrict__ C)
{
    GEMM_PROLOGUE(A, Bt)
    const int col16 = lane & 15, g4 = (lane >> 4) << 2;
    #pragma unroll
    for (int mm = 0; mm < 4; ++mm) {
        const int m = m0 + wr * 64 + mm * 16 + col16;
        #pragma unroll
        for (int nn = 0; nn < 4; ++nn) {
            const int n_a = n0 + wc * 64 + nn * 16 + g4;
            *reinterpret_cast<float4*>(&C[(size_t)m * 1024 + n_a]) =
                make_float4(acc[mm][nn][0], acc[mm][nn][1], acc[mm][nn][2], acc[mm][nn][3]);
        }
    }
}

// ---------- MFMA flash attention, 1-wave blocks for occupancy ----------
// grid 4096 x 64 threads. Wave owns 32 q rows (col=lane&31), 32-key tiles.
// Same verified 32x32x16 fragment math as round 5 (S^T = mfma(K,Q), P^T via
// cvt_pk + permlane32_swap, O^T = mfma(V^T, P^T)). No LDS, no barriers.
// Exact rescale-skip: only rescale O/l when the running max actually grows.
__global__ __launch_bounds__(64) void attn5_kernel(
    const u16* __restrict__ Q, const u16* __restrict__ K, const u16* __restrict__ Vt,
    const int* __restrict__ pos, u16* __restrict__ AO)
{
    const int bid = blockIdx.x;
    const int wg  = ((bid & 7) << 9) + (bid >> 3);   // bijective XCD swizzle (4096 % 8 == 0)
    const int bh  = wg >> 6;                          // 8 heads per XCD chunk
    const int qw  = 63 - (wg & 63);                   // longest prefixes dispatched first (LPT)
    const int b = bh >> 4, h = bh & 15;
    const int lane = threadIdx.x;
    const int col = lane & 31, hi = lane >> 5;
    const int i0 = qw * 32;

    // per-lane exact prefix bound for row (i0+col): first idx with pos > pos_row
    int bnd;
    {
        const int target = pos[b * 2048 + i0 + col];
        int lo = 0, hic = 2048;
        #pragma unroll
        for (int it = 0; it < 12; ++it) {
            const int mid = (lo + hic) >> 1;
            if (lo < hic) { if (pos[b * 2048 + mid] <= target) lo = mid + 1; else hic = mid; }
        }
        bnd = lo;
    }
    int bmax = bnd, bmin = bnd;
    #pragma unroll
    for (int s = 1; s < 32; s <<= 1) {
        bmax = max(bmax, __shfl_xor(bmax, s));
        bmin = min(bmin, __shfl_xor(bmin, s));
    }

    const size_t kvrow = (size_t)bh * 2048;
    const size_t vrow  = (size_t)bh * 64;

    // Q B-frags (pre-scaled by 0.125*log2e)
    bf16x8 qf[4];
    #pragma unroll
    for (int ds = 0; ds < 4; ++ds)
        qf[ds] = *(const bf16x8*)&Q[(kvrow + i0 + col) * 64 + ds * 16 + hi * 8];

    const int hi4 = 4 * hi;

    float mrun = -INFINITY, lrun = 0.f;
    f32x16 oT0, oT1;
    #pragma unroll
    for (int i = 0; i < 16; ++i) { oT0[i] = 0.f; oT1[i] = 0.f; }

    for (int j0 = 0; j0 < bmax; j0 += 32) {
        // load K / V^T fragments for this tile
        bf16x8 kf[4], vfa[2], vfb[2];
        #pragma unroll
        for (int ds = 0; ds < 4; ++ds)
            kf[ds] = *(const bf16x8*)&K[(kvrow + j0 + col) * 64 + ds * 16 + hi * 8];
        #pragma unroll
        for (int kh = 0; kh < 2; ++kh) {
            vfa[kh] = *(const bf16x8*)&Vt[(vrow + col) * 2048 + j0 + kh * 16 + hi * 8];
            vfb[kh] = *(const bf16x8*)&Vt[(vrow + 32 + col) * 2048 + j0 + kh * 16 + hi * 8];
        }

        // S^T = K · Q^T over d=64
        f32x16 st;
        #pragma unroll
        for (int i = 0; i < 16; ++i) st[i] = 0.f;
        #pragma unroll
        for (int ds = 0; ds < 4; ++ds)
            st = __builtin_amdgcn_mfma_f32_32x32x16_bf16(kf[ds], qf[ds], st, 0, 0, 0);

        // mask: k_global >= bnd(q)  (boundary tiles only)
        if (j0 + 32 > bmin) {
            #pragma unroll
            for (int r = 0; r < 16; ++r) {
                const int kg = j0 + ((r & 3) + 8 * (r >> 2)) + hi4;
                if (kg >= bnd) st[r] = -INFINITY;
            }
        }

        // online softmax (exp2 domain), exact rescale-skip
        float rm = st[0];
        #pragma unroll
        for (int r = 1; r < 16; ++r) rm = fmaxf(rm, st[r]);
        rm = fmaxf(rm, __shfl_xor(rm, 32));
        if (__any(rm > mrun)) {
            const float mnew = fmaxf(mrun, rm);
            const float factor = __builtin_amdgcn_exp2f(mrun - mnew);
            mrun = mnew;
            lrun *= factor;
            #pragma unroll
            for (int i = 0; i < 16; ++i) { oT0[i] *= factor; oT1[i] *= factor; }
        }
        float psum = 0.f;
        #pragma unroll
        for (int r = 0; r < 16; ++r) {
            const float p = __builtin_amdgcn_exp2f(st[r] - mrun);
            st[r] = p;
            psum += p;
        }
        psum += __shfl_xor(psum, 32);
        lrun += psum;

        // pack P^T: W[r] covers k-pair {8*(r>>1) + 2*(r&1) + 4hi, +1}
        u32 W[8];
        #pragma unroll
        for (int r = 0; r < 8; ++r) W[r] = cvtpk(st[2 * r], st[2 * r + 1]);

        u32 a0 = W[0], b0 = W[2]; pswap(a0, b0);
        u32 a1 = W[1], b1 = W[3]; pswap(a1, b1);
        u32 a2 = W[4], b2 = W[6]; pswap(a2, b2);
        u32 a3 = W[5], b3 = W[7]; pswap(a3, b3);
        union { u32 w[4]; bf16x8 v; } p0, p1;
        p0.w[0] = a0; p0.w[1] = a1; p0.w[2] = b0; p0.w[3] = b1;
        p1.w[0] = a2; p1.w[1] = a3; p1.w[2] = b2; p1.w[3] = b3;

        // PV: O^T += V^T · P^T
        oT0 = __builtin_amdgcn_mfma_f32_32x32x16_bf16(vfa[0], p0.v, oT0, 0, 0, 0);
        oT0 = __builtin_amdgcn_mfma_f32_32x32x16_bf16(vfa[1], p1.v, oT0, 0, 0, 0);
        oT1 = __builtin_amdgcn_mfma_f32_32x32x16_bf16(vfb[0], p0.v, oT1, 0, 0, 0);
        oT1 = __builtin_amdgcn_mfma_f32_32x32x16_bf16(vfb[1], p1.v, oT1, 0, 0, 0);
    }

    // epilogue: scale by 1/l, pack d-pairs, write AO bf16 [t][h*64+d]
    const float inv = 1.f / lrun;
    u16* dst = &AO[((size_t)(b * 2048 + i0 + col)) * 1024 + h * 64];
    #pragma unroll
    for (int w = 0; w < 8; ++w) {
        const int dloc = 8 * (w >> 1) + 2 * (w & 1) + hi4;
        *reinterpret_cast<u32*>(&dst[dloc])      = cvtpk(oT0[2 * w] * inv, oT0[2 * w + 1] * inv);
        *reinterpret_cast<u32*>(&dst[32 + dloc]) = cvtpk(oT1[2 * w] * inv, oT1[2 * w + 1] * inv);
    }
}

extern "C" void kernel_launch(void* const* d_in, const int* in_sizes, int n_in,
                              void* d_out, int out_size, void* d_ws, size_t ws_size,
                              hipStream_t stream) {
    (void)in_sizes; (void)n_in; (void)out_size; (void)ws_size;
    const float* x    = (const float*)d_in[0];
    const int*   pos  = (const int*)d_in[1];
    const float* Wqkv = (const float*)d_in[2];
    const float* Wout = (const float*)d_in[3];
    float* out = (float*)d_out;

    char* ws = (char*)d_ws;
    u16* xb    = (u16*)(ws);                 // 16 MB (aliased as AO after gemm1 consumes it)
    u16* WqkvT = (u16*)(ws + 16777216);      // 6 MB
    u16* WoutT = (u16*)(ws + 23068672);      // 2 MB
    u16* Qb    = (u16*)(ws + 25165824);      // 16 MB bf16 [bh][t][d], pre-scaled
    u16* Kb    = (u16*)(ws + 41943040);      // 16 MB bf16 [bh][t][d]
    u16* Vtb   = (u16*)(ws + 58720256);      // 16 MB bf16 [bh][d][t] (written transposed by gemm)
    u16* AO    = xb;

    convx_kernel<<<dim3(M1 * ND / (256 * 4)), dim3(256), 0, stream>>>(x, xb);
    tconv_kernel<<<dim3(N3D / 32, ND / 32), dim3(32, 8), 0, stream>>>(Wqkv, WqkvT, ND, N3D);
    tconv_kernel<<<dim3(ND / 32, ND / 32), dim3(32, 8), 0, stream>>>(Wout, WoutT, ND, ND);
    gemm_qkv_kernel<<<dim3(N3D / 128, M1 / 128), dim3(256), 0, stream>>>(xb, WqkvT, Qb, Kb, Vtb);
    attn5_kernel<<<dim3(4096), dim3(64), 0, stream>>>(Qb, Kb, Vtb, pos, AO);
    gemm_out_kernel<<<dim3(ND / 128, M1 / 128), dim3(256), 0, stream>>>(AO, WoutT, out);
}